// Round 8
// baseline (608.346 us; speedup 1.0000x reference)
//
#include <hip/hip_runtime.h>

// NuclideGNN: 3-layer GCN on MI355X.
// R7: gather rewritten wave-per-node: zero LDS, zero barriers, register-staged
//     edges broadcast via shfl, shfl_xor butterfly reduce. Kills the 3.2M LDS
//     bank-conflict cycles and the per-node block-sync/reduce overhead.

#define NN 100000
#define NE 3200000
#define FI 7
#define HD 128
#define DD 64
#define EPS 1e-5f
#define NB 196                        // buckets of 512 dst nodes (dst>>9)
#define EPB 8192                      // edges per P1/P3 block (256 thr x 32)
#define NBLK ((NE + EPB - 1) / EPB)   // 391

typedef float float2v __attribute__((ext_vector_type(2)));
typedef short short8 __attribute__((ext_vector_type(8)));
typedef float f32x4 __attribute__((ext_vector_type(4)));

__device__ __forceinline__ unsigned char f2fp8(float f) {
    return (unsigned char)(__builtin_amdgcn_cvt_pk_fp8_f32(f, f, 0, false) & 0xFF);
}
__device__ __forceinline__ unsigned short f2bf(float f) {
    unsigned u = __float_as_uint(f);
    u += 0x7FFF + ((u >> 16) & 1);  // RNE
    return (unsigned short)(u >> 16);
}

// ---------------- CSR build: two-level bucket sort ----------------

__global__ __launch_bounds__(256) void p1_bucket_hist(const int* __restrict__ ei,
                                                      int* __restrict__ bcnt,
                                                      int* __restrict__ blk_off) {
    __shared__ int h[NB];
    const int t = threadIdx.x;
    for (int b = t; b < NB; b += 256) h[b] = 0;
    __syncthreads();
    const int base = blockIdx.x * EPB;
#pragma unroll 4
    for (int i = 0; i < EPB / 256; ++i) {
        int e = base + i * 256 + t;
        if (e < NE) atomicAdd(&h[ei[NE + e] >> 9], 1);
    }
    __syncthreads();
    for (int b = t; b < NB; b += 256) {
        int c = h[b];
        blk_off[blockIdx.x * NB + b] = c ? atomicAdd(&bcnt[b], c) : 0;
    }
}

__global__ __launch_bounds__(256) void p2_bucket_scan(const int* __restrict__ bcnt,
                                                      int* __restrict__ bstart) {
    __shared__ int sh[256];
    const int t = threadIdx.x;
    const int myc = (t < NB) ? bcnt[t] : 0;
    sh[t] = myc;
    __syncthreads();
    for (int off = 1; off < 256; off <<= 1) {
        int v = (t >= off) ? sh[t - off] : 0;
        __syncthreads();
        sh[t] += v;
        __syncthreads();
    }
    if (t < NB) bstart[t] = sh[t] - myc;  // exclusive prefix
    if (t == 0) bstart[NB] = NE;
}

__global__ __launch_bounds__(256) void p3_bin(const int* __restrict__ ei,
                                              const int* __restrict__ bstart,
                                              const int* __restrict__ blk_off,
                                              int* __restrict__ ebin) {
    __shared__ int cur[NB];
    const int t = threadIdx.x;
    for (int b = t; b < NB; b += 256)
        cur[b] = bstart[b] + blk_off[blockIdx.x * NB + b];
    __syncthreads();
    const int base = blockIdx.x * EPB;
#pragma unroll 4
    for (int i = 0; i < EPB / 256; ++i) {
        int e = base + i * 256 + t;
        if (e < NE) {
            int s = ei[e];       // src (< 2^17)
            int d = ei[NE + e];  // dst
            int p = atomicAdd(&cur[d >> 9], 1);
            ebin[p] = ((d & 511) << 23) | s;  // pack local-dst | src
        }
    }
}

__global__ __launch_bounds__(512) void p4_finalize(const int* __restrict__ bstart,
                                                   const int* __restrict__ ebin,
                                                   int* __restrict__ esrc,
                                                   int* __restrict__ rowstart,
                                                   float* __restrict__ dinv) {
    __shared__ int lh[512];  // local degree
    __shared__ int sc[512];  // scan buffer
    __shared__ int lc[512];  // local cursor
    const int t = threadIdx.x;
    const int b = blockIdx.x;
    const int n0 = b << 9;
    const int ebase = bstart[b];
    const int ecnt = bstart[b + 1] - ebase;
    lh[t] = 0;
    __syncthreads();
    for (int i = t; i < ecnt; i += 512)
        atomicAdd(&lh[((unsigned)ebin[ebase + i]) >> 23], 1);
    __syncthreads();
    const int c = lh[t];
    sc[t] = c;
    __syncthreads();
    for (int off = 1; off < 512; off <<= 1) {
        int v = (t >= off) ? sc[t - off] : 0;
        __syncthreads();
        sc[t] += v;
        __syncthreads();
    }
    const int excl = ebase + sc[t] - c;  // global rowstart for node n0+t
    lc[t] = excl;
    const int node = n0 + t;
    if (node < NN) {
        rowstart[node] = excl;
        dinv[node] = rsqrtf((float)c + 1.0f);  // deg includes self-loop
    }
    if (b == NB - 1 && t == 0) rowstart[NN] = NE;
    __syncthreads();
    for (int i = t; i < ecnt; i += 512) {
        int v = ebin[ebase + i];
        int p = atomicAdd(&lc[((unsigned)v) >> 23], 1);
        esrc[p] = v & 0x7FFFFF;  // writes land in a 65KB L2-hot window
    }
}

// --------- input projection: h = relu(x @ W_in + b_in), fp32 + bf16 ---------

__global__ __launch_bounds__(256) void inproj_kernel(const float* __restrict__ x,
                                                     const float* __restrict__ W_in,
                                                     const float* __restrict__ b_in,
                                                     float* __restrict__ hA,
                                                     unsigned short* __restrict__ hAbf) {
    int n = blockIdx.x * 2 + (threadIdx.x >> 7);
    int j = threadIdx.x & 127;
    float acc = b_in[j];
#pragma unroll
    for (int f = 0; f < FI; ++f) acc += x[n * FI + f] * W_in[f * HD + j];
    acc = fmaxf(acc, 0.f);
    hA[n * HD + j] = acc;
    hAbf[n * HD + j] = f2bf(acc);
}

// -------- W pre-swizzle into MFMA B-fragment order (bf16) -------------------

template <int DO>
__global__ __launch_bounds__(64) void wprep(const float* __restrict__ W,
                                            unsigned short* __restrict__ Wf) {
    const int lane = threadIdx.x;
    const int nt = blockIdx.x >> 2;
    const int ks = blockIdx.x & 3;
    short8 o;
#pragma unroll
    for (int j = 0; j < 8; ++j)
        o[j] = (short)f2bf(W[(ks * 32 + (lane >> 4) * 8 + j) * DO + nt * 16 + (lane & 15)]);
    *(short8*)(Wf + ((size_t)blockIdx.x * 64 + lane) * 8) = o;
}

// -------- MFMA GEMM: B[N,DO](fp8) = A[N,128](bf16) @ W(bf16 frags) ----------

template <int DO>
__global__ __launch_bounds__(256) void gemm_mfma(const unsigned short* __restrict__ A,
                                                 const unsigned short* __restrict__ Wf,
                                                 unsigned char* __restrict__ B) {
    constexpr int CT = DO / 64;  // col-tiles per wave: 2 (DO=128) or 1 (DO=64)
    const int tid = threadIdx.x;
    const int wave = tid >> 6;
    const int lane = tid & 63;
    const int n0 = blockIdx.x * 32;
    short8 bfrag[CT][4];
#pragma unroll
    for (int ct = 0; ct < CT; ++ct)
#pragma unroll
        for (int ks = 0; ks < 4; ++ks)
            bfrag[ct][ks] = *(const short8*)(Wf + ((size_t)(((wave * CT + ct) * 4 + ks) * 64) + lane) * 8);
#pragma unroll
    for (int rt = 0; rt < 2; ++rt) {
        const int arow = n0 + rt * 16 + (lane & 15);
        short8 afrag[4];
#pragma unroll
        for (int ks = 0; ks < 4; ++ks)
            afrag[ks] = *(const short8*)(A + (size_t)arow * HD + ks * 32 + ((lane >> 4) & 3) * 8);
        f32x4 acc[CT];
#pragma unroll
        for (int ct = 0; ct < CT; ++ct) acc[ct] = (f32x4){0.f, 0.f, 0.f, 0.f};
#pragma unroll
        for (int ks = 0; ks < 4; ++ks)
#pragma unroll
            for (int ct = 0; ct < CT; ++ct)
                acc[ct] = __builtin_amdgcn_mfma_f32_16x16x32_bf16(afrag[ks], bfrag[ct][ks], acc[ct], 0, 0, 0);
#pragma unroll
        for (int ct = 0; ct < CT; ++ct) {
            const int ocol = (wave * CT + ct) * 16 + (lane & 15);
#pragma unroll
            for (int r = 0; r < 4; ++r) {
                const int orow = n0 + rt * 16 + (lane >> 4) * 4 + r;
                B[(size_t)orow * DO + ocol] = f2fp8(acc[ct][r]);
            }
        }
    }
}

// ---------- fused gather: wave per node, LDS-free, shfl-staged ----------
// Lane l owns uint-column (l%UW) and edge-slot (l/UW). EP=64/UW edges/iter.
// Edge ids+dinv staged in registers (1 coalesced esrc load / 64 edges),
// broadcast per-edge via __shfl; reduce via shfl_xor butterfly; epilogue on
// lanes<UW. 4 independent waves per 256-thr block, no barriers at all.

template <int DO, bool RELU_RES>
__global__ __launch_bounds__(256) void gather_wave(const unsigned char* __restrict__ hXW,
                                                   float* __restrict__ resOut,
                                                   unsigned short* __restrict__ resBf,
                                                   const int* __restrict__ rowstart,
                                                   const int* __restrict__ esrc,
                                                   const float* __restrict__ dinv,
                                                   const float* __restrict__ bias,
                                                   const float* __restrict__ g,
                                                   const float* __restrict__ be,
                                                   const float* __restrict__ m,
                                                   const float* __restrict__ v) {
    constexpr int UW = DO / 4;    // uints per row: 32 (DO=128) / 16 (DO=64)
    constexpr int EP = 64 / UW;   // edges per iteration: 2 / 4
    const int t = threadIdx.x;
    const int lane = t & 63;
    const int n = blockIdx.x * 4 + (t >> 6);
    const int sub = lane / UW;    // edge slot within iteration
    const int cw = lane % UW;     // uint column
    const int rs = rowstart[n];
    const int re = rowstart[n + 1];
    const float dn = dinv[n];
    float4 acc0 = {0.f, 0.f, 0.f, 0.f};
    float4 acc1 = {0.f, 0.f, 0.f, 0.f};
    for (int base = rs; base < re; base += 64) {
        const int c = min(64, re - base);
        int e = 0;
        float dv = 0.f;
        if (lane < c) {
            e = esrc[base + lane];
            dv = dinv[e];
        }
        for (int k = 0; k < c; k += 2 * EP) {
            const int j0 = k + sub;
            const int j1 = k + EP + sub;
            const int s0 = __shfl(e, j0, 64);
            const float w0 = __shfl(dv, j0, 64);
            const int s1 = __shfl(e, j1, 64);
            const float w1 = __shfl(dv, j1, 64);
            if (j0 < c) {
                const unsigned u = *(const unsigned*)(hXW + (size_t)s0 * DO + cw * 4);
                const float2v lo = __builtin_amdgcn_cvt_pk_f32_fp8(u, false);
                const float2v hi = __builtin_amdgcn_cvt_pk_f32_fp8(u, true);
                acc0.x += lo.x * w0; acc0.y += lo.y * w0;
                acc0.z += hi.x * w0; acc0.w += hi.y * w0;
            }
            if (j1 < c) {
                const unsigned u = *(const unsigned*)(hXW + (size_t)s1 * DO + cw * 4);
                const float2v lo = __builtin_amdgcn_cvt_pk_f32_fp8(u, false);
                const float2v hi = __builtin_amdgcn_cvt_pk_f32_fp8(u, true);
                acc1.x += lo.x * w1; acc1.y += lo.y * w1;
                acc1.z += hi.x * w1; acc1.w += hi.y * w1;
            }
        }
    }
    acc0.x += acc1.x; acc0.y += acc1.y; acc0.z += acc1.z; acc0.w += acc1.w;
    // butterfly: combine edge-slots (same cw across sub groups)
#pragma unroll
    for (int off = 32; off >= UW; off >>= 1) {
        acc0.x += __shfl_xor(acc0.x, off, 64);
        acc0.y += __shfl_xor(acc0.y, off, 64);
        acc0.z += __shfl_xor(acc0.z, off, 64);
        acc0.w += __shfl_xor(acc0.w, off, 64);
    }
    if (lane < UW) {
        const int q = cw;
        const unsigned su = *(const unsigned*)(hXW + (size_t)n * DO + q * 4);
        const float2v slo = __builtin_amdgcn_cvt_pk_f32_fp8(su, false);
        const float2v shi = __builtin_amdgcn_cvt_pk_f32_fp8(su, true);
        const float4 b4 = *(const float4*)(bias + q * 4);
        const float4 g4 = *(const float4*)(g + q * 4);
        const float4 be4 = *(const float4*)(be + q * 4);
        const float4 m4 = *(const float4*)(m + q * 4);
        const float4 v4 = *(const float4*)(v + q * 4);
        float4 val;
        val.x = (acc0.x + dn * slo.x) * dn + b4.x;
        val.y = (acc0.y + dn * slo.y) * dn + b4.y;
        val.z = (acc0.z + dn * shi.x) * dn + b4.z;
        val.w = (acc0.w + dn * shi.y) * dn + b4.w;
        val.x = (val.x - m4.x) * (g4.x * rsqrtf(v4.x + EPS)) + be4.x;
        val.y = (val.y - m4.y) * (g4.y * rsqrtf(v4.y + EPS)) + be4.y;
        val.z = (val.z - m4.z) * (g4.z * rsqrtf(v4.z + EPS)) + be4.z;
        val.w = (val.w - m4.w) * (g4.w * rsqrtf(v4.w + EPS)) + be4.w;
        float4* outp = (float4*)(resOut + (size_t)n * DO + q * 4);
        if (RELU_RES) {
            const float4 r = *outp;
            val.x = fmaxf(val.x, 0.f) + r.x;
            val.y = fmaxf(val.y, 0.f) + r.y;
            val.z = fmaxf(val.z, 0.f) + r.z;
            val.w = fmaxf(val.w, 0.f) + r.w;
            ushort4 bf;
            bf.x = f2bf(val.x); bf.y = f2bf(val.y);
            bf.z = f2bf(val.z); bf.w = f2bf(val.w);
            *(ushort4*)(resBf + (size_t)n * DO + q * 4) = bf;
        }
        *outp = val;
    }
}

// ---------------- launch ----------------

extern "C" void kernel_launch(void* const* d_in, const int* in_sizes, int n_in,
                              void* d_out, int out_size, void* d_ws, size_t ws_size,
                              hipStream_t stream) {
    const float* x    = (const float*)d_in[0];
    const int*   ei   = (const int*)d_in[1];
    const float* W_in = (const float*)d_in[2];
    const float* b_in = (const float*)d_in[3];
    const float* Wl[3] = {(const float*)d_in[4], (const float*)d_in[10], (const float*)d_in[16]};
    const float* bl[3] = {(const float*)d_in[5], (const float*)d_in[11], (const float*)d_in[17]};
    const float* gl[3] = {(const float*)d_in[6], (const float*)d_in[12], (const float*)d_in[18]};
    const float* bel[3] = {(const float*)d_in[7], (const float*)d_in[13], (const float*)d_in[19]};
    const float* ml[3] = {(const float*)d_in[8], (const float*)d_in[14], (const float*)d_in[20]};
    const float* vl[3] = {(const float*)d_in[9], (const float*)d_in[15], (const float*)d_in[21]};
    float* out = (float*)d_out;

    char* ws = (char*)d_ws;
    size_t off = 0;
    auto carve = [&](size_t bytes) {
        void* p = ws + off;
        off += (bytes + 255) & ~(size_t)255;
        return p;
    };
    int*   bcnt     = (int*)carve(NB * sizeof(int));
    int*   bstart   = (int*)carve((NB + 1) * sizeof(int));
    int*   blk_off  = (int*)carve((size_t)NBLK * NB * sizeof(int));
    int*   rowstart = (int*)carve((NN + 1) * sizeof(int));
    float* dinv     = (float*)carve(NN * sizeof(float));
    int*   esrc     = (int*)carve((size_t)NE * sizeof(int));
    float* hA       = (float*)carve((size_t)NN * HD * sizeof(float));
    unsigned short* hAbf = (unsigned short*)carve((size_t)NN * HD * sizeof(unsigned short));
    unsigned char* hB = (unsigned char*)carve((size_t)NN * HD);
    int*   ebin     = (int*)carve((size_t)NE * sizeof(int));
    unsigned short* wf0 = (unsigned short*)carve((size_t)HD * HD * sizeof(unsigned short));
    unsigned short* wf1 = (unsigned short*)carve((size_t)HD * HD * sizeof(unsigned short));
    unsigned short* wf2 = (unsigned short*)carve((size_t)HD * DD * sizeof(unsigned short));
    (void)ws_size;

    hipMemsetAsync(bcnt, 0, NB * sizeof(int), stream);

    wprep<128><<<32, 64, 0, stream>>>(Wl[0], wf0);
    wprep<128><<<32, 64, 0, stream>>>(Wl[1], wf1);
    wprep<64><<<16, 64, 0, stream>>>(Wl[2], wf2);

    p1_bucket_hist<<<NBLK, 256, 0, stream>>>(ei, bcnt, blk_off);
    p2_bucket_scan<<<1, 256, 0, stream>>>(bcnt, bstart);
    p3_bin<<<NBLK, 256, 0, stream>>>(ei, bstart, blk_off, ebin);
    p4_finalize<<<NB, 512, 0, stream>>>(bstart, ebin, esrc, rowstart, dinv);

    inproj_kernel<<<NN / 2, 256, 0, stream>>>(x, W_in, b_in, hA, hAbf);

    // layer 0
    gemm_mfma<128><<<NN / 32, 256, 0, stream>>>(hAbf, wf0, hB);
    gather_wave<128, true><<<NN / 4, 256, 0, stream>>>(hB, hA, hAbf, rowstart, esrc, dinv,
                                                       bl[0], gl[0], bel[0], ml[0], vl[0]);
    // layer 1
    gemm_mfma<128><<<NN / 32, 256, 0, stream>>>(hAbf, wf1, hB);
    gather_wave<128, true><<<NN / 4, 256, 0, stream>>>(hB, hA, hAbf, rowstart, esrc, dinv,
                                                       bl[1], gl[1], bel[1], ml[1], vl[1]);
    // layer 2 (BN only, write d_out)
    gemm_mfma<64><<<NN / 32, 256, 0, stream>>>(hAbf, wf2, hB);
    gather_wave<64, false><<<NN / 4, 256, 0, stream>>>(hB, out, (unsigned short*)nullptr,
                                                       rowstart, esrc, dinv,
                                                       bl[2], gl[2], bel[2], ml[2], vl[2]);
}

// Round 9
// 534.120 us; speedup vs baseline: 1.1390x; 1.1390x over previous
//
#include <hip/hip_runtime.h>

// NuclideGNN: 3-layer GCN on MI355X.
// R8: revert R7's shfl gather (regression: per-edge ds_bpermute > amortized
//     LDS stage). R6 gather + SoA conflict-free reduce; p2 folded into p3/p4;
//     wprep fused to 1 launch.

#define NN 100000
#define NE 3200000
#define FI 7
#define HD 128
#define DD 64
#define EPS 1e-5f
#define NB 196                        // buckets of 512 dst nodes (dst>>9)
#define EPB 8192                      // edges per P1/P3 block (256 thr x 32)
#define NBLK ((NE + EPB - 1) / EPB)   // 391

typedef float float2v __attribute__((ext_vector_type(2)));
typedef short short8 __attribute__((ext_vector_type(8)));
typedef float f32x4 __attribute__((ext_vector_type(4)));

__device__ __forceinline__ unsigned char f2fp8(float f) {
    return (unsigned char)(__builtin_amdgcn_cvt_pk_fp8_f32(f, f, 0, false) & 0xFF);
}
__device__ __forceinline__ unsigned short f2bf(float f) {
    unsigned u = __float_as_uint(f);
    u += 0x7FFF + ((u >> 16) & 1);  // RNE
    return (unsigned short)(u >> 16);
}

// ---------------- CSR build: two-level bucket sort ----------------

__global__ __launch_bounds__(256) void p1_bucket_hist(const int* __restrict__ ei,
                                                      int* __restrict__ bcnt,
                                                      int* __restrict__ blk_off) {
    __shared__ int h[NB];
    const int t = threadIdx.x;
    for (int b = t; b < NB; b += 256) h[b] = 0;
    __syncthreads();
    const int base = blockIdx.x * EPB;
#pragma unroll 4
    for (int i = 0; i < EPB / 256; ++i) {
        int e = base + i * 256 + t;
        if (e < NE) atomicAdd(&h[ei[NE + e] >> 9], 1);
    }
    __syncthreads();
    for (int b = t; b < NB; b += 256) {
        int c = h[b];
        blk_off[blockIdx.x * NB + b] = c ? atomicAdd(&bcnt[b], c) : 0;
    }
}

// p3: each block scans bcnt locally (replaces p2), then bins its edge chunk.
__global__ __launch_bounds__(256) void p3_bin(const int* __restrict__ ei,
                                              const int* __restrict__ bcnt,
                                              const int* __restrict__ blk_off,
                                              int* __restrict__ ebin) {
    __shared__ int sh[256];
    __shared__ int cur[NB];
    const int t = threadIdx.x;
    const int myc = (t < NB) ? bcnt[t] : 0;
    sh[t] = myc;
    __syncthreads();
    for (int off = 1; off < 256; off <<= 1) {
        int v = (t >= off) ? sh[t - off] : 0;
        __syncthreads();
        sh[t] += v;
        __syncthreads();
    }
    if (t < NB) cur[t] = sh[t] - myc + blk_off[blockIdx.x * NB + t];
    __syncthreads();
    const int base = blockIdx.x * EPB;
#pragma unroll 4
    for (int i = 0; i < EPB / 256; ++i) {
        int e = base + i * 256 + t;
        if (e < NE) {
            int s = ei[e];       // src (< 2^17)
            int d = ei[NE + e];  // dst
            int p = atomicAdd(&cur[d >> 9], 1);
            ebin[p] = ((d & 511) << 23) | s;  // pack local-dst | src
        }
    }
}

// p4: local bucket scan (replaces p2) + per-bucket hist/scan/scatter.
__global__ __launch_bounds__(512) void p4_finalize(const int* __restrict__ bcnt,
                                                   const int* __restrict__ ebin,
                                                   int* __restrict__ esrc,
                                                   int* __restrict__ rowstart,
                                                   float* __restrict__ dinv) {
    __shared__ int sh[256];  // bucket-count scan
    __shared__ int lh[512];  // local degree
    __shared__ int sc[512];  // scan buffer
    __shared__ int lc[512];  // local cursor
    const int t = threadIdx.x;
    const int b = blockIdx.x;
    if (t < 256) sh[t] = (t < NB) ? bcnt[t] : 0;
    __syncthreads();
    for (int off = 1; off < 256; off <<= 1) {
        int v = (t < 256 && t >= off) ? sh[t - off] : 0;
        __syncthreads();
        if (t < 256) sh[t] += v;
        __syncthreads();
    }
    const int ecnt = bcnt[b];
    const int ebase = sh[b] - ecnt;
    const int n0 = b << 9;
    lh[t] = 0;
    __syncthreads();
    for (int i = t; i < ecnt; i += 512)
        atomicAdd(&lh[((unsigned)ebin[ebase + i]) >> 23], 1);
    __syncthreads();
    const int c = lh[t];
    sc[t] = c;
    __syncthreads();
    for (int off = 1; off < 512; off <<= 1) {
        int v = (t >= off) ? sc[t - off] : 0;
        __syncthreads();
        sc[t] += v;
        __syncthreads();
    }
    const int excl = ebase + sc[t] - c;  // global rowstart for node n0+t
    lc[t] = excl;
    const int node = n0 + t;
    if (node < NN) {
        rowstart[node] = excl;
        dinv[node] = rsqrtf((float)c + 1.0f);  // deg includes self-loop
    }
    if (b == NB - 1 && t == 0) rowstart[NN] = NE;
    __syncthreads();
    for (int i = t; i < ecnt; i += 512) {
        int v = ebin[ebase + i];
        int p = atomicAdd(&lc[((unsigned)v) >> 23], 1);
        esrc[p] = v & 0x7FFFFF;  // writes land in a 65KB L2-hot window
    }
}

// --------- input projection: h = relu(x @ W_in + b_in), fp32 + bf16 ---------

__global__ __launch_bounds__(256) void inproj_kernel(const float* __restrict__ x,
                                                     const float* __restrict__ W_in,
                                                     const float* __restrict__ b_in,
                                                     float* __restrict__ hA,
                                                     unsigned short* __restrict__ hAbf) {
    int n = blockIdx.x * 2 + (threadIdx.x >> 7);
    int j = threadIdx.x & 127;
    float acc = b_in[j];
#pragma unroll
    for (int f = 0; f < FI; ++f) acc += x[n * FI + f] * W_in[f * HD + j];
    acc = fmaxf(acc, 0.f);
    hA[n * HD + j] = acc;
    hAbf[n * HD + j] = f2bf(acc);
}

// -------- W pre-swizzle into MFMA B-fragment order (bf16), 3 mats fused -----
// blocks 0..31 -> W0(128), 32..63 -> W1(128), 64..79 -> W2(64)

__global__ __launch_bounds__(64) void wprep_all(const float* __restrict__ W0,
                                                const float* __restrict__ W1,
                                                const float* __restrict__ W2,
                                                unsigned short* __restrict__ wf0,
                                                unsigned short* __restrict__ wf1,
                                                unsigned short* __restrict__ wf2) {
    const int blk = blockIdx.x;
    const float* W;
    unsigned short* Wf;
    int DO, rel;
    if (blk < 32) { W = W0; Wf = wf0; DO = 128; rel = blk; }
    else if (blk < 64) { W = W1; Wf = wf1; DO = 128; rel = blk - 32; }
    else { W = W2; Wf = wf2; DO = 64; rel = blk - 64; }
    const int lane = threadIdx.x;
    const int nt = rel >> 2;
    const int ks = rel & 3;
    short8 o;
#pragma unroll
    for (int j = 0; j < 8; ++j)
        o[j] = (short)f2bf(W[(ks * 32 + (lane >> 4) * 8 + j) * DO + nt * 16 + (lane & 15)]);
    *(short8*)(Wf + ((size_t)rel * 64 + lane) * 8) = o;
}

// -------- MFMA GEMM: B[N,DO](fp8) = A[N,128](bf16) @ W(bf16 frags) ----------

template <int DO>
__global__ __launch_bounds__(256) void gemm_mfma(const unsigned short* __restrict__ A,
                                                 const unsigned short* __restrict__ Wf,
                                                 unsigned char* __restrict__ B) {
    constexpr int CT = DO / 64;  // col-tiles per wave: 2 (DO=128) or 1 (DO=64)
    const int tid = threadIdx.x;
    const int wave = tid >> 6;
    const int lane = tid & 63;
    const int n0 = blockIdx.x * 32;
    short8 bfrag[CT][4];
#pragma unroll
    for (int ct = 0; ct < CT; ++ct)
#pragma unroll
        for (int ks = 0; ks < 4; ++ks)
            bfrag[ct][ks] = *(const short8*)(Wf + ((size_t)(((wave * CT + ct) * 4 + ks) * 64) + lane) * 8);
#pragma unroll
    for (int rt = 0; rt < 2; ++rt) {
        const int arow = n0 + rt * 16 + (lane & 15);
        short8 afrag[4];
#pragma unroll
        for (int ks = 0; ks < 4; ++ks)
            afrag[ks] = *(const short8*)(A + (size_t)arow * HD + ks * 32 + ((lane >> 4) & 3) * 8);
        f32x4 acc[CT];
#pragma unroll
        for (int ct = 0; ct < CT; ++ct) acc[ct] = (f32x4){0.f, 0.f, 0.f, 0.f};
#pragma unroll
        for (int ks = 0; ks < 4; ++ks)
#pragma unroll
            for (int ct = 0; ct < CT; ++ct)
                acc[ct] = __builtin_amdgcn_mfma_f32_16x16x32_bf16(afrag[ks], bfrag[ct][ks], acc[ct], 0, 0, 0);
#pragma unroll
        for (int ct = 0; ct < CT; ++ct) {
            const int ocol = (wave * CT + ct) * 16 + (lane & 15);
#pragma unroll
            for (int r = 0; r < 4; ++r) {
                const int orow = n0 + rt * 16 + (lane >> 4) * 4 + r;
                B[(size_t)orow * DO + ocol] = f2fp8(acc[ct][r]);
            }
        }
    }
}

// ---------- fused gather + self-loop + bias + BN (+ ReLU + residual) ----------
// Block (128 thr) per dst node. hXW fp8 [N,DO]; thread t: col-group q=t&(CG-1)
// (8 cols, uint2), edge-group grp=t/CG. SoA sred (conflict-free) reduce.
// MUST be launched with 128 threads (edge tile == 128).

template <int DO, bool RELU_RES>
__global__ __launch_bounds__(128) void gather_kernel(const unsigned char* __restrict__ hXW,
                                                     float* __restrict__ resOut,
                                                     unsigned short* __restrict__ resBf,
                                                     const int* __restrict__ rowstart,
                                                     const int* __restrict__ esrc,
                                                     const float* __restrict__ dinv,
                                                     const float* __restrict__ bias,
                                                     const float* __restrict__ g,
                                                     const float* __restrict__ be,
                                                     const float* __restrict__ m,
                                                     const float* __restrict__ v) {
    constexpr int CG = DO / 8;    // 16 (DO=128) or 8 (DO=64) col-groups
    constexpr int NG = 128 / CG;  // 8 or 16 edge groups
    constexpr int QN = DO / 4;    // output col-quads
    __shared__ int s_idx[128];
    __shared__ float s_dv[128];
    __shared__ float sred[8][128];  // SoA: component c of thread t at [c][t]
    const int n = blockIdx.x;
    const int t = threadIdx.x;
    const int rs = rowstart[n];
    const int re = rowstart[n + 1];
    const float dn = dinv[n];
    const int q = t & (CG - 1);
    const int grp = t / CG;
    float4 a0l = {0.f, 0.f, 0.f, 0.f}, a0h = {0.f, 0.f, 0.f, 0.f};
    float4 a1l = {0.f, 0.f, 0.f, 0.f}, a1h = {0.f, 0.f, 0.f, 0.f};
    for (int base = rs; base < re; base += 128) {
        const int c = min(128, re - base);
        __syncthreads();
        if (t < c) {
            int s = esrc[base + t];
            s_idx[t] = s;
            s_dv[t] = dinv[s];
        }
        __syncthreads();
        for (int j = grp; j < c; j += 2 * NG) {
            {
                const uint2 u = *(const uint2*)(hXW + (size_t)s_idx[j] * DO + q * 8);
                const float w = s_dv[j];
                const float2v l0 = __builtin_amdgcn_cvt_pk_f32_fp8(u.x, false);
                const float2v h0 = __builtin_amdgcn_cvt_pk_f32_fp8(u.x, true);
                const float2v l1 = __builtin_amdgcn_cvt_pk_f32_fp8(u.y, false);
                const float2v h1 = __builtin_amdgcn_cvt_pk_f32_fp8(u.y, true);
                a0l.x += l0.x * w; a0l.y += l0.y * w; a0l.z += h0.x * w; a0l.w += h0.y * w;
                a0h.x += l1.x * w; a0h.y += l1.y * w; a0h.z += h1.x * w; a0h.w += h1.y * w;
            }
            if (j + NG < c) {
                const uint2 u = *(const uint2*)(hXW + (size_t)s_idx[j + NG] * DO + q * 8);
                const float w = s_dv[j + NG];
                const float2v l0 = __builtin_amdgcn_cvt_pk_f32_fp8(u.x, false);
                const float2v h0 = __builtin_amdgcn_cvt_pk_f32_fp8(u.x, true);
                const float2v l1 = __builtin_amdgcn_cvt_pk_f32_fp8(u.y, false);
                const float2v h1 = __builtin_amdgcn_cvt_pk_f32_fp8(u.y, true);
                a1l.x += l0.x * w; a1l.y += l0.y * w; a1l.z += h0.x * w; a1l.w += h0.y * w;
                a1h.x += l1.x * w; a1h.y += l1.y * w; a1h.z += h1.x * w; a1h.w += h1.y * w;
            }
        }
    }
    a0l.x += a1l.x; a0l.y += a1l.y; a0l.z += a1l.z; a0l.w += a1l.w;
    a0h.x += a1h.x; a0h.y += a1h.y; a0h.z += a1h.z; a0h.w += a1h.w;
    __syncthreads();  // protect s_idx/s_dv reuse vs sred aliasing lifetimes
    sred[0][t] = a0l.x; sred[1][t] = a0l.y; sred[2][t] = a0l.z; sred[3][t] = a0l.w;
    sred[4][t] = a0h.x; sred[5][t] = a0h.y; sred[6][t] = a0h.z; sred[7][t] = a0h.w;
    __syncthreads();
    if (t < QN) {
        const int qq = t >> 1, h = t & 1;
        float4 sum = {0.f, 0.f, 0.f, 0.f};
#pragma unroll
        for (int k = 0; k < NG; ++k) {
            const int u = k * CG + qq;
            sum.x += sred[h * 4 + 0][u];
            sum.y += sred[h * 4 + 1][u];
            sum.z += sred[h * 4 + 2][u];
            sum.w += sred[h * 4 + 3][u];
        }
        const unsigned su = *(const unsigned*)(hXW + (size_t)n * DO + t * 4);
        const float2v slo = __builtin_amdgcn_cvt_pk_f32_fp8(su, false);
        const float2v shi = __builtin_amdgcn_cvt_pk_f32_fp8(su, true);
        const float4 b4 = *(const float4*)(bias + t * 4);
        const float4 g4 = *(const float4*)(g + t * 4);
        const float4 be4 = *(const float4*)(be + t * 4);
        const float4 m4 = *(const float4*)(m + t * 4);
        const float4 v4 = *(const float4*)(v + t * 4);
        float4 val;
        val.x = (sum.x + dn * slo.x) * dn + b4.x;
        val.y = (sum.y + dn * slo.y) * dn + b4.y;
        val.z = (sum.z + dn * shi.x) * dn + b4.z;
        val.w = (sum.w + dn * shi.y) * dn + b4.w;
        val.x = (val.x - m4.x) * (g4.x * rsqrtf(v4.x + EPS)) + be4.x;
        val.y = (val.y - m4.y) * (g4.y * rsqrtf(v4.y + EPS)) + be4.y;
        val.z = (val.z - m4.z) * (g4.z * rsqrtf(v4.z + EPS)) + be4.z;
        val.w = (val.w - m4.w) * (g4.w * rsqrtf(v4.w + EPS)) + be4.w;
        float4* outp = (float4*)(resOut + (size_t)n * DO + t * 4);
        if (RELU_RES) {
            const float4 r = *outp;
            val.x = fmaxf(val.x, 0.f) + r.x;
            val.y = fmaxf(val.y, 0.f) + r.y;
            val.z = fmaxf(val.z, 0.f) + r.z;
            val.w = fmaxf(val.w, 0.f) + r.w;
            ushort4 bf;
            bf.x = f2bf(val.x); bf.y = f2bf(val.y);
            bf.z = f2bf(val.z); bf.w = f2bf(val.w);
            *(ushort4*)(resBf + (size_t)n * DO + t * 4) = bf;
        }
        *outp = val;
    }
}

// ---------------- launch ----------------

extern "C" void kernel_launch(void* const* d_in, const int* in_sizes, int n_in,
                              void* d_out, int out_size, void* d_ws, size_t ws_size,
                              hipStream_t stream) {
    const float* x    = (const float*)d_in[0];
    const int*   ei   = (const int*)d_in[1];
    const float* W_in = (const float*)d_in[2];
    const float* b_in = (const float*)d_in[3];
    const float* Wl[3] = {(const float*)d_in[4], (const float*)d_in[10], (const float*)d_in[16]};
    const float* bl[3] = {(const float*)d_in[5], (const float*)d_in[11], (const float*)d_in[17]};
    const float* gl[3] = {(const float*)d_in[6], (const float*)d_in[12], (const float*)d_in[18]};
    const float* bel[3] = {(const float*)d_in[7], (const float*)d_in[13], (const float*)d_in[19]};
    const float* ml[3] = {(const float*)d_in[8], (const float*)d_in[14], (const float*)d_in[20]};
    const float* vl[3] = {(const float*)d_in[9], (const float*)d_in[15], (const float*)d_in[21]};
    float* out = (float*)d_out;

    char* ws = (char*)d_ws;
    size_t off = 0;
    auto carve = [&](size_t bytes) {
        void* p = ws + off;
        off += (bytes + 255) & ~(size_t)255;
        return p;
    };
    int*   bcnt     = (int*)carve(NB * sizeof(int));
    int*   blk_off  = (int*)carve((size_t)NBLK * NB * sizeof(int));
    int*   rowstart = (int*)carve((NN + 1) * sizeof(int));
    float* dinv     = (float*)carve(NN * sizeof(float));
    int*   esrc     = (int*)carve((size_t)NE * sizeof(int));
    float* hA       = (float*)carve((size_t)NN * HD * sizeof(float));
    unsigned short* hAbf = (unsigned short*)carve((size_t)NN * HD * sizeof(unsigned short));
    unsigned char* hB = (unsigned char*)carve((size_t)NN * HD);
    int*   ebin     = (int*)carve((size_t)NE * sizeof(int));
    unsigned short* wf0 = (unsigned short*)carve((size_t)HD * HD * sizeof(unsigned short));
    unsigned short* wf1 = (unsigned short*)carve((size_t)HD * HD * sizeof(unsigned short));
    unsigned short* wf2 = (unsigned short*)carve((size_t)HD * DD * sizeof(unsigned short));
    (void)ws_size;

    hipMemsetAsync(bcnt, 0, NB * sizeof(int), stream);

    wprep_all<<<80, 64, 0, stream>>>(Wl[0], Wl[1], Wl[2], wf0, wf1, wf2);

    p1_bucket_hist<<<NBLK, 256, 0, stream>>>(ei, bcnt, blk_off);
    p3_bin<<<NBLK, 256, 0, stream>>>(ei, bcnt, blk_off, ebin);
    p4_finalize<<<NB, 512, 0, stream>>>(bcnt, ebin, esrc, rowstart, dinv);

    inproj_kernel<<<NN / 2, 256, 0, stream>>>(x, W_in, b_in, hA, hAbf);

    // layer 0
    gemm_mfma<128><<<NN / 32, 256, 0, stream>>>(hAbf, wf0, hB);
    gather_kernel<128, true><<<NN, 128, 0, stream>>>(hB, hA, hAbf, rowstart, esrc, dinv,
                                                     bl[0], gl[0], bel[0], ml[0], vl[0]);
    // layer 1
    gemm_mfma<128><<<NN / 32, 256, 0, stream>>>(hAbf, wf1, hB);
    gather_kernel<128, true><<<NN, 128, 0, stream>>>(hB, hA, hAbf, rowstart, esrc, dinv,
                                                     bl[1], gl[1], bel[1], ml[1], vl[1]);
    // layer 2 (BN only, write d_out); 128 threads (edge tile = 128)
    gemm_mfma<64><<<NN / 32, 256, 0, stream>>>(hAbf, wf2, hB);
    gather_kernel<64, false><<<NN, 128, 0, stream>>>(hB, out, (unsigned short*)nullptr,
                                                     rowstart, esrc, dinv,
                                                     bl[2], gl[2], bel[2], ml[2], vl[2]);
}

// Round 10
// 513.181 us; speedup vs baseline: 1.1854x; 1.0408x over previous
//
#include <hip/hip_runtime.h>

// NuclideGNN: 3-layer GCN on MI355X.
// R9: (a) hB rows pre-scaled by dinv[src] in GEMM epilogue -> gather is pure
//     row-sum: s_dv staging + per-edge weight broadcast gone (halves per-edge
//     LDS reads; conflicts 3.2M->~1.6M predicted); (b) p1+p3 fused into one
//     LDS-staged pass with fixed 20k-edge bucket windows (drops a 12.8MB
//     edge re-read + a dispatch).

#define NN 100000
#define NE 3200000
#define FI 7
#define HD 128
#define DD 64
#define EPS 1e-5f
#define NB 196                        // buckets of 512 dst nodes (dst>>9)
#define EPB 8192                      // edges per pA block (256 thr x 32)
#define NBLK ((NE + EPB - 1) / EPB)   // 391
#define EMAX 20000                    // fixed ebin window per bucket (max ~16.7k)

typedef float float2v __attribute__((ext_vector_type(2)));
typedef short short8 __attribute__((ext_vector_type(8)));
typedef float f32x4 __attribute__((ext_vector_type(4)));

__device__ __forceinline__ unsigned char f2fp8(float f) {
    return (unsigned char)(__builtin_amdgcn_cvt_pk_fp8_f32(f, f, 0, false) & 0xFF);
}
__device__ __forceinline__ unsigned short f2bf(float f) {
    unsigned u = __float_as_uint(f);
    u += 0x7FFF + ((u >> 16) & 1);  // RNE
    return (unsigned short)(u >> 16);
}

// ---------------- CSR build ----------------
// pA: single pass: stage dst in LDS, hist, reserve fixed bucket windows,
//     scatter packed (local-dst | src) records.

__global__ __launch_bounds__(256) void pA_bin(const int* __restrict__ ei,
                                              int* __restrict__ bcnt,
                                              int* __restrict__ ebin) {
    __shared__ int sdst[EPB];   // 32 KB
    __shared__ int hcur[NB];
    const int t = threadIdx.x;
    for (int b = t; b < NB; b += 256) hcur[b] = 0;
    __syncthreads();
    const int base = blockIdx.x * EPB;
    const int cnt = min(EPB, NE - base);
    for (int i = t; i < cnt; i += 256) {
        int d = ei[NE + base + i];
        sdst[i] = d;
        atomicAdd(&hcur[d >> 9], 1);
    }
    __syncthreads();
    for (int b = t; b < NB; b += 256) {
        int c = hcur[b];
        hcur[b] = (c ? atomicAdd(&bcnt[b], c) : 0) + b * EMAX;
    }
    __syncthreads();
    for (int i = t; i < cnt; i += 256) {
        int s = ei[base + i];
        int d = sdst[i];
        int p = atomicAdd(&hcur[d >> 9], 1);
        ebin[p] = ((d & 511) << 23) | s;
    }
}

// p4: local bucket scan (dense esrc offsets) + per-bucket hist/scan/scatter.
__global__ __launch_bounds__(512) void p4_finalize(const int* __restrict__ bcnt,
                                                   const int* __restrict__ ebin,
                                                   int* __restrict__ esrc,
                                                   int* __restrict__ rowstart,
                                                   float* __restrict__ dinv) {
    __shared__ int sh[256];  // bucket-count scan
    __shared__ int lh[512];  // local degree
    __shared__ int sc[512];  // scan buffer
    __shared__ int lc[512];  // local cursor
    const int t = threadIdx.x;
    const int b = blockIdx.x;
    if (t < 256) sh[t] = (t < NB) ? bcnt[t] : 0;
    __syncthreads();
    for (int off = 1; off < 256; off <<= 1) {
        int v = (t < 256 && t >= off) ? sh[t - off] : 0;
        __syncthreads();
        if (t < 256) sh[t] += v;
        __syncthreads();
    }
    const int ecnt = bcnt[b];
    const int ebase = sh[b] - ecnt;   // dense esrc base for this bucket
    const int rbase = b * EMAX;       // padded ebin read base
    const int n0 = b << 9;
    lh[t] = 0;
    __syncthreads();
    for (int i = t; i < ecnt; i += 512)
        atomicAdd(&lh[((unsigned)ebin[rbase + i]) >> 23], 1);
    __syncthreads();
    const int c = lh[t];
    sc[t] = c;
    __syncthreads();
    for (int off = 1; off < 512; off <<= 1) {
        int v = (t >= off) ? sc[t - off] : 0;
        __syncthreads();
        sc[t] += v;
        __syncthreads();
    }
    const int excl = ebase + sc[t] - c;  // global rowstart for node n0+t
    lc[t] = excl;
    const int node = n0 + t;
    if (node < NN) {
        rowstart[node] = excl;
        dinv[node] = rsqrtf((float)c + 1.0f);  // deg includes self-loop
    }
    if (b == NB - 1 && t == 0) rowstart[NN] = NE;
    __syncthreads();
    for (int i = t; i < ecnt; i += 512) {
        int v = ebin[rbase + i];
        int p = atomicAdd(&lc[((unsigned)v) >> 23], 1);
        esrc[p] = v & 0x7FFFFF;  // writes land in a 65KB L2-hot window
    }
}

// --------- input projection: h = relu(x @ W_in + b_in), fp32 + bf16 ---------

__global__ __launch_bounds__(256) void inproj_kernel(const float* __restrict__ x,
                                                     const float* __restrict__ W_in,
                                                     const float* __restrict__ b_in,
                                                     float* __restrict__ hA,
                                                     unsigned short* __restrict__ hAbf) {
    int n = blockIdx.x * 2 + (threadIdx.x >> 7);
    int j = threadIdx.x & 127;
    float acc = b_in[j];
#pragma unroll
    for (int f = 0; f < FI; ++f) acc += x[n * FI + f] * W_in[f * HD + j];
    acc = fmaxf(acc, 0.f);
    hA[n * HD + j] = acc;
    hAbf[n * HD + j] = f2bf(acc);
}

// -------- W pre-swizzle into MFMA B-fragment order (bf16), 3 mats fused -----

__global__ __launch_bounds__(64) void wprep_all(const float* __restrict__ W0,
                                                const float* __restrict__ W1,
                                                const float* __restrict__ W2,
                                                unsigned short* __restrict__ wf0,
                                                unsigned short* __restrict__ wf1,
                                                unsigned short* __restrict__ wf2) {
    const int blk = blockIdx.x;
    const float* W;
    unsigned short* Wf;
    int DO, rel;
    if (blk < 32) { W = W0; Wf = wf0; DO = 128; rel = blk; }
    else if (blk < 64) { W = W1; Wf = wf1; DO = 128; rel = blk - 32; }
    else { W = W2; Wf = wf2; DO = 64; rel = blk - 64; }
    const int lane = threadIdx.x;
    const int nt = rel >> 2;
    const int ks = rel & 3;
    short8 o;
#pragma unroll
    for (int j = 0; j < 8; ++j)
        o[j] = (short)f2bf(W[(ks * 32 + (lane >> 4) * 8 + j) * DO + nt * 16 + (lane & 15)]);
    *(short8*)(Wf + ((size_t)rel * 64 + lane) * 8) = o;
}

// -------- MFMA GEMM: B[N,DO](fp8) = (A[N,128](bf16) @ W) * dinv[row] --------
// Pre-scales each output row by dinv[row] so the gather is a pure row-sum.

template <int DO>
__global__ __launch_bounds__(256) void gemm_mfma(const unsigned short* __restrict__ A,
                                                 const unsigned short* __restrict__ Wf,
                                                 const float* __restrict__ dinv,
                                                 unsigned char* __restrict__ B) {
    constexpr int CT = DO / 64;  // col-tiles per wave: 2 (DO=128) or 1 (DO=64)
    const int tid = threadIdx.x;
    const int wave = tid >> 6;
    const int lane = tid & 63;
    const int n0 = blockIdx.x * 32;
    short8 bfrag[CT][4];
#pragma unroll
    for (int ct = 0; ct < CT; ++ct)
#pragma unroll
        for (int ks = 0; ks < 4; ++ks)
            bfrag[ct][ks] = *(const short8*)(Wf + ((size_t)(((wave * CT + ct) * 4 + ks) * 64) + lane) * 8);
#pragma unroll
    for (int rt = 0; rt < 2; ++rt) {
        const int arow = n0 + rt * 16 + (lane & 15);
        short8 afrag[4];
#pragma unroll
        for (int ks = 0; ks < 4; ++ks)
            afrag[ks] = *(const short8*)(A + (size_t)arow * HD + ks * 32 + ((lane >> 4) & 3) * 8);
        f32x4 acc[CT];
#pragma unroll
        for (int ct = 0; ct < CT; ++ct) acc[ct] = (f32x4){0.f, 0.f, 0.f, 0.f};
#pragma unroll
        for (int ks = 0; ks < 4; ++ks)
#pragma unroll
            for (int ct = 0; ct < CT; ++ct)
                acc[ct] = __builtin_amdgcn_mfma_f32_16x16x32_bf16(afrag[ks], bfrag[ct][ks], acc[ct], 0, 0, 0);
#pragma unroll
        for (int r = 0; r < 4; ++r) {
            const int orow = n0 + rt * 16 + (lane >> 4) * 4 + r;
            const float dv = dinv[orow];
#pragma unroll
            for (int ct = 0; ct < CT; ++ct) {
                const int ocol = (wave * CT + ct) * 16 + (lane & 15);
                B[(size_t)orow * DO + ocol] = f2fp8(acc[ct][r] * dv);
            }
        }
    }
}

// ---------- fused gather (pure row-sum) + self-loop + bias + BN (+relu/res) --
// Block (128 thr) per dst node. hXW fp8 [N,DO] PRE-SCALED by dinv[src].
// thread t: col-group q=t&(CG-1) (8 cols, uint2), edge-group grp=t/CG.
// Only s_idx staged (no per-edge weight). MUST launch with 128 threads.

template <int DO, bool RELU_RES>
__global__ __launch_bounds__(128) void gather_kernel(const unsigned char* __restrict__ hXW,
                                                     float* __restrict__ resOut,
                                                     unsigned short* __restrict__ resBf,
                                                     const int* __restrict__ rowstart,
                                                     const int* __restrict__ esrc,
                                                     const float* __restrict__ dinv,
                                                     const float* __restrict__ bias,
                                                     const float* __restrict__ g,
                                                     const float* __restrict__ be,
                                                     const float* __restrict__ m,
                                                     const float* __restrict__ v) {
    constexpr int CG = DO / 8;    // 16 (DO=128) or 8 (DO=64) col-groups
    constexpr int NG = 128 / CG;  // 8 or 16 edge groups
    constexpr int QN = DO / 4;    // output col-quads
    __shared__ int s_idx[128];
    __shared__ float sred[8][128];  // SoA partials
    const int n = blockIdx.x;
    const int t = threadIdx.x;
    const int rs = rowstart[n];
    const int re = rowstart[n + 1];
    const float dn = dinv[n];
    const int q = t & (CG - 1);
    const int grp = t / CG;
    float4 a0l = {0.f, 0.f, 0.f, 0.f}, a0h = {0.f, 0.f, 0.f, 0.f};
    float4 a1l = {0.f, 0.f, 0.f, 0.f}, a1h = {0.f, 0.f, 0.f, 0.f};
    for (int base = rs; base < re; base += 128) {
        const int c = min(128, re - base);
        __syncthreads();
        if (t < c) s_idx[t] = esrc[base + t];
        __syncthreads();
        for (int j = grp; j < c; j += 2 * NG) {
            {
                const uint2 u = *(const uint2*)(hXW + (size_t)s_idx[j] * DO + q * 8);
                const float2v l0 = __builtin_amdgcn_cvt_pk_f32_fp8(u.x, false);
                const float2v h0 = __builtin_amdgcn_cvt_pk_f32_fp8(u.x, true);
                const float2v l1 = __builtin_amdgcn_cvt_pk_f32_fp8(u.y, false);
                const float2v h1 = __builtin_amdgcn_cvt_pk_f32_fp8(u.y, true);
                a0l.x += l0.x; a0l.y += l0.y; a0l.z += h0.x; a0l.w += h0.y;
                a0h.x += l1.x; a0h.y += l1.y; a0h.z += h1.x; a0h.w += h1.y;
            }
            if (j + NG < c) {
                const uint2 u = *(const uint2*)(hXW + (size_t)s_idx[j + NG] * DO + q * 8);
                const float2v l0 = __builtin_amdgcn_cvt_pk_f32_fp8(u.x, false);
                const float2v h0 = __builtin_amdgcn_cvt_pk_f32_fp8(u.x, true);
                const float2v l1 = __builtin_amdgcn_cvt_pk_f32_fp8(u.y, false);
                const float2v h1 = __builtin_amdgcn_cvt_pk_f32_fp8(u.y, true);
                a1l.x += l0.x; a1l.y += l0.y; a1l.z += h0.x; a1l.w += h0.y;
                a1h.x += l1.x; a1h.y += l1.y; a1h.z += h1.x; a1h.w += h1.y;
            }
        }
    }
    a0l.x += a1l.x; a0l.y += a1l.y; a0l.z += a1l.z; a0l.w += a1l.w;
    a0h.x += a1h.x; a0h.y += a1h.y; a0h.z += a1h.z; a0h.w += a1h.w;
    __syncthreads();
    sred[0][t] = a0l.x; sred[1][t] = a0l.y; sred[2][t] = a0l.z; sred[3][t] = a0l.w;
    sred[4][t] = a0h.x; sred[5][t] = a0h.y; sred[6][t] = a0h.z; sred[7][t] = a0h.w;
    __syncthreads();
    if (t < QN) {
        const int qq = t >> 1, h = t & 1;
        float4 sum = {0.f, 0.f, 0.f, 0.f};
#pragma unroll
        for (int k = 0; k < NG; ++k) {
            const int u = k * CG + qq;
            sum.x += sred[h * 4 + 0][u];
            sum.y += sred[h * 4 + 1][u];
            sum.z += sred[h * 4 + 2][u];
            sum.w += sred[h * 4 + 3][u];
        }
        // self-loop: stored row n is already dinv[n]*XW[n]
        const unsigned su = *(const unsigned*)(hXW + (size_t)n * DO + t * 4);
        const float2v slo = __builtin_amdgcn_cvt_pk_f32_fp8(su, false);
        const float2v shi = __builtin_amdgcn_cvt_pk_f32_fp8(su, true);
        const float4 b4 = *(const float4*)(bias + t * 4);
        const float4 g4 = *(const float4*)(g + t * 4);
        const float4 be4 = *(const float4*)(be + t * 4);
        const float4 m4 = *(const float4*)(m + t * 4);
        const float4 v4 = *(const float4*)(v + t * 4);
        float4 val;
        val.x = (sum.x + slo.x) * dn + b4.x;
        val.y = (sum.y + slo.y) * dn + b4.y;
        val.z = (sum.z + shi.x) * dn + b4.z;
        val.w = (sum.w + shi.y) * dn + b4.w;
        val.x = (val.x - m4.x) * (g4.x * rsqrtf(v4.x + EPS)) + be4.x;
        val.y = (val.y - m4.y) * (g4.y * rsqrtf(v4.y + EPS)) + be4.y;
        val.z = (val.z - m4.z) * (g4.z * rsqrtf(v4.z + EPS)) + be4.z;
        val.w = (val.w - m4.w) * (g4.w * rsqrtf(v4.w + EPS)) + be4.w;
        float4* outp = (float4*)(resOut + (size_t)n * DO + t * 4);
        if (RELU_RES) {
            const float4 r = *outp;
            val.x = fmaxf(val.x, 0.f) + r.x;
            val.y = fmaxf(val.y, 0.f) + r.y;
            val.z = fmaxf(val.z, 0.f) + r.z;
            val.w = fmaxf(val.w, 0.f) + r.w;
            ushort4 bf;
            bf.x = f2bf(val.x); bf.y = f2bf(val.y);
            bf.z = f2bf(val.z); bf.w = f2bf(val.w);
            *(ushort4*)(resBf + (size_t)n * DO + t * 4) = bf;
        }
        *outp = val;
    }
}

// ---------------- launch ----------------

extern "C" void kernel_launch(void* const* d_in, const int* in_sizes, int n_in,
                              void* d_out, int out_size, void* d_ws, size_t ws_size,
                              hipStream_t stream) {
    const float* x    = (const float*)d_in[0];
    const int*   ei   = (const int*)d_in[1];
    const float* W_in = (const float*)d_in[2];
    const float* b_in = (const float*)d_in[3];
    const float* Wl[3] = {(const float*)d_in[4], (const float*)d_in[10], (const float*)d_in[16]};
    const float* bl[3] = {(const float*)d_in[5], (const float*)d_in[11], (const float*)d_in[17]};
    const float* gl[3] = {(const float*)d_in[6], (const float*)d_in[12], (const float*)d_in[18]};
    const float* bel[3] = {(const float*)d_in[7], (const float*)d_in[13], (const float*)d_in[19]};
    const float* ml[3] = {(const float*)d_in[8], (const float*)d_in[14], (const float*)d_in[20]};
    const float* vl[3] = {(const float*)d_in[9], (const float*)d_in[15], (const float*)d_in[21]};
    float* out = (float*)d_out;

    char* ws = (char*)d_ws;
    size_t off = 0;
    auto carve = [&](size_t bytes) {
        void* p = ws + off;
        off += (bytes + 255) & ~(size_t)255;
        return p;
    };
    int*   bcnt     = (int*)carve(NB * sizeof(int));
    int*   rowstart = (int*)carve((NN + 1) * sizeof(int));
    float* dinv     = (float*)carve(NN * sizeof(float));
    int*   esrc     = (int*)carve((size_t)NE * sizeof(int));
    float* hA       = (float*)carve((size_t)NN * HD * sizeof(float));
    unsigned short* hAbf = (unsigned short*)carve((size_t)NN * HD * sizeof(unsigned short));
    unsigned char* hB = (unsigned char*)carve((size_t)NN * HD);
    int*   ebin     = (int*)carve((size_t)NB * EMAX * sizeof(int));
    unsigned short* wf0 = (unsigned short*)carve((size_t)HD * HD * sizeof(unsigned short));
    unsigned short* wf1 = (unsigned short*)carve((size_t)HD * HD * sizeof(unsigned short));
    unsigned short* wf2 = (unsigned short*)carve((size_t)HD * DD * sizeof(unsigned short));
    (void)ws_size;

    hipMemsetAsync(bcnt, 0, NB * sizeof(int), stream);

    wprep_all<<<80, 64, 0, stream>>>(Wl[0], Wl[1], Wl[2], wf0, wf1, wf2);

    pA_bin<<<NBLK, 256, 0, stream>>>(ei, bcnt, ebin);
    p4_finalize<<<NB, 512, 0, stream>>>(bcnt, ebin, esrc, rowstart, dinv);

    inproj_kernel<<<NN / 2, 256, 0, stream>>>(x, W_in, b_in, hA, hAbf);

    // layer 0
    gemm_mfma<128><<<NN / 32, 256, 0, stream>>>(hAbf, wf0, dinv, hB);
    gather_kernel<128, true><<<NN, 128, 0, stream>>>(hB, hA, hAbf, rowstart, esrc, dinv,
                                                     bl[0], gl[0], bel[0], ml[0], vl[0]);
    // layer 1
    gemm_mfma<128><<<NN / 32, 256, 0, stream>>>(hAbf, wf1, dinv, hB);
    gather_kernel<128, true><<<NN, 128, 0, stream>>>(hB, hA, hAbf, rowstart, esrc, dinv,
                                                     bl[1], gl[1], bel[1], ml[1], vl[1]);
    // layer 2 (BN only, write d_out); 128 threads (edge tile = 128)
    gemm_mfma<64><<<NN / 32, 256, 0, stream>>>(hAbf, wf2, dinv, hB);
    gather_kernel<64, false><<<NN, 128, 0, stream>>>(hB, out, (unsigned short*)nullptr,
                                                     rowstart, esrc, dinv,
                                                     bl[2], gl[2], bel[2], ml[2], vl[2]);
}